// Round 1
// baseline (1943.615 us; speedup 1.0000x reference)
//
#include <hip/hip_runtime.h>
#include <hip/hip_fp16.h>

#define NN 100000
#define EE 1600000
#define HH 64
#define GG 64
#define NBK 391    // buckets of 256 nodes: dst>>8
#define CAP 8192   // fixed bucket capacity (mean load 4092, max ~4400)

typedef _Float16 f16x8 __attribute__((ext_vector_type(8)));
typedef float f32x4 __attribute__((ext_vector_type(4)));

// ---------------- workspace layout (bytes) ----------------
// (free)    : int[NN]          @ 0         (old rowStart, unused)
// (free)    : int[NN]          @ 400000    (old rowLen, unused)
// dinv      : float[NN]        @ 800000
// pairs     : int[NBK*CAP]     @ 1200000   (ends 14012288) (src<<8 | dst&255), bucket-major
// u         : half[4][NN][16]  @ 14012288  (ends 26812288)
// hb(half)  : half[NN*64]      @ 26812288  (ends 39612288)
// Wh        : half[3][16384]   @ 52424576  (32KB/layer, ends 52522880)
// gsum      : float[4096]      @ 52522880
// gcnt      : float[64]        @ 52539264
// bcur      : int[NBK]         @ 52539520
//
// Failed-experiment ledger (keep!):
//  R8  col-split gemm: VALUBusy 6.8%, 2x slower (halved ILP per row-read)
//  R13 producer-local gemm: agg FETCH unchanged (L2 invalidated at dispatch edge)
//  R15 warm_slice + nt hints: agg 46->69us, FETCH 31->41MB (nt evicts srcs)
//  R17 fp32 eighth-tables: VALU 43->29% but bytes/edge 2x -> agg 46->83us
//  => R16 fp16-quarter gather (46us, 31MB) was the converged PULL structure.
//  R18 (this round): PUSH-scatter agg — bucket-owned LDS f32 accumulator
//      (acc[256][17], ds_add_f32), divergence-free edge streams, depth-4 MLP;
//      bsort deleted (bdeg histogram replaces it).

static inline int cdiv_h(int a, int b) { return (a + b - 1) / b; }

// ---- partition edges into fixed-capacity buckets (391 blocks x 4096 edges) ----
__global__ __launch_bounds__(256) void bplace_kernel(const int* __restrict__ ei,
                                                     int* __restrict__ bcur,
                                                     int* __restrict__ pairs) {
    __shared__ int h[NBK];
    __shared__ int boff[NBK];
    for (int t = threadIdx.x; t < NBK; t += 256) h[t] = 0;
    __syncthreads();
    int base = blockIdx.x * 4096;
#pragma unroll 4
    for (int i = 0; i < 16; i++) {
        int e = base + i * 256 + threadIdx.x;
        if (e < EE) atomicAdd(&h[ei[EE + e] >> 8], 1);
    }
    __syncthreads();
    for (int t = threadIdx.x; t < NBK; t += 256) {
        int c = h[t];
        boff[t] = c ? (t * CAP + atomicAdd(&bcur[t], c)) : 0;
        h[t] = 0;  // reuse as running cursor
    }
    __syncthreads();
#pragma unroll 4
    for (int i = 0; i < 16; i++) {
        int e = base + i * 256 + threadIdx.x;
        if (e < EE) {
            int s0 = ei[e];
            int d = ei[EE + e];
            int b = d >> 8;
            int p = boff[b] + atomicAdd(&h[b], 1);
            pairs[p] = (s0 << 8) | (d & 255);
        }
    }
}

// ---- per-bucket degree histogram -> dinv (replaces bsort; push needs no edge sort) ----
__global__ __launch_bounds__(256) void bdeg_kernel(const int* __restrict__ pairs,
                                                   const int* __restrict__ bcur,
                                                   float* __restrict__ dinv) {
    int b = blockIdx.x;
    int t = threadIdx.x;
    __shared__ int cnt[256];
    cnt[t] = 0;
    __syncthreads();
    int e0 = b * CAP;
    int e1 = e0 + bcur[b];
    for (int e = e0 + t; e < e1; e += 256) atomicAdd(&cnt[pairs[e] & 255], 1);
    __syncthreads();
    int n = (b << 8) + t;
    if (n < NN) dinv[n] = rsqrtf((float)cnt[t] + 1.0f);
}

// ---- merged prep: blocks 0-2 = W swizzle (hi/lo B-frags); blocks 3+ = gcnt ----
__global__ __launch_bounds__(256) void prep_kernel(const float* __restrict__ W0,
                                                   const float* __restrict__ W1,
                                                   const float* __restrict__ W2,
                                                   _Float16* __restrict__ Wh,
                                                   const int* __restrict__ batch,
                                                   float* __restrict__ gcnt) {
    if (blockIdx.x < 3) {
        const float* Wl = (blockIdx.x == 0) ? W0 : (blockIdx.x == 1) ? W1 : W2;
        _Float16* out = Wh + blockIdx.x * 16384;
        for (int c = threadIdx.x; c < 512; c += 256) {  // t(4) x h(2) x lane(64)
            int t = c >> 7;
            int h = (c >> 6) & 1;
            int lane = c & 63;
            int quad = lane >> 4;
            int n = lane & 15;
#pragma unroll
            for (int j = 0; j < 8; j++) {
                int k = h * 32 + quad * 8 + j;
                float w = Wl[k * 64 + t * 16 + n];
                _Float16 hi = (_Float16)w;
                _Float16 lo = (_Float16)(w - (float)hi);
                out[(((t * 2 + h) * 2 + 0) * 64 + lane) * 8 + j] = hi;
                out[(((t * 2 + h) * 2 + 1) * 64 + lane) * 8 + j] = lo;
            }
        }
    } else {
        __shared__ int h[GG];
        if (threadIdx.x < GG) h[threadIdx.x] = 0;
        __syncthreads();
        int n = (blockIdx.x - 3) * 256 + threadIdx.x;
        if (n < NN) atomicAdd(&h[batch[n]], 1);
        __syncthreads();
        if (threadIdx.x < GG && h[threadIdx.x])
            atomicAdd(&gcnt[threadIdx.x], (float)h[threadIdx.x]);
    }
}

// ---- MFMA gemm core (A frags in registers -> u quarter tables via LDS) ----
__device__ __forceinline__ void gemm_core(f16x8 a0, f16x8 a1,
                                          const _Float16* __restrict__ Whl,
                                          const float* __restrict__ dinv,
                                          _Float16* __restrict__ u,
                                          int wv, int lane, int n0, bool active,
                                          _Float16 (*lds)[4][16][16]) {
    int m = lane & 15;
    int quad = lane >> 4;
    if (active) {
        f32x4 acc[4];
#pragma unroll
        for (int t = 0; t < 4; t++) acc[t] = (f32x4){0.f, 0.f, 0.f, 0.f};
#pragma unroll
        for (int t = 0; t < 4; t++) {
            f16x8 bh0 = *(const f16x8*)(Whl + (((t * 2 + 0) * 2 + 0) * 64 + lane) * 8);
            f16x8 bl0 = *(const f16x8*)(Whl + (((t * 2 + 0) * 2 + 1) * 64 + lane) * 8);
            f16x8 bh1 = *(const f16x8*)(Whl + (((t * 2 + 1) * 2 + 0) * 64 + lane) * 8);
            f16x8 bl1 = *(const f16x8*)(Whl + (((t * 2 + 1) * 2 + 1) * 64 + lane) * 8);
            acc[t] = __builtin_amdgcn_mfma_f32_16x16x32_f16(a0, bh0, acc[t], 0, 0, 0);
            acc[t] = __builtin_amdgcn_mfma_f32_16x16x32_f16(a0, bl0, acc[t], 0, 0, 0);
            acc[t] = __builtin_amdgcn_mfma_f32_16x16x32_f16(a1, bh1, acc[t], 0, 0, 0);
            acc[t] = __builtin_amdgcn_mfma_f32_16x16x32_f16(a1, bl1, acc[t], 0, 0, 0);
        }
        // D layout: col = lane&15 (= feature), row = quad*4 + reg (= node) [m89/m91]
        float4 dv4 = *(const float4*)(dinv + n0 + quad * 4);
        const float* dvp = (const float*)&dv4;
#pragma unroll
        for (int t = 0; t < 4; t++)
#pragma unroll
            for (int i = 0; i < 4; i++)
                lds[wv][t][quad * 4 + i][m] = (_Float16)(acc[t][i] * dvp[i]);
    }
    __syncthreads();
    if (active) {
        int t = lane >> 4;
        int node = lane & 15;
        f16x8 v0 = *(const f16x8*)&lds[wv][t][node][0];
        f16x8 v1 = *(const f16x8*)&lds[wv][t][node][8];
        _Float16* dst = u + ((size_t)t * NN + n0 + node) * 16;
        *(f16x8*)dst = v0;
        *(f16x8*)(dst + 8) = v1;
    }
}

// layer 0: fp32 x rows, convert to A-frags in-register (no cast pass needed)
__global__ __launch_bounds__(256) void gemm_mfma_f32_kernel(const float* __restrict__ hin,
                                                            const _Float16* __restrict__ Whl,
                                                            const float* __restrict__ dinv,
                                                            _Float16* __restrict__ u) {
    __shared__ _Float16 lds[4][4][16][16];  // 8KB
    int wv = threadIdx.x >> 6;
    int wid = blockIdx.x * 4 + wv;
    int lane = threadIdx.x & 63;
    int m = lane & 15;
    int quad = lane >> 4;
    bool active = (wid < NN / 16);
    int n0 = wid * 16;
    f16x8 a0 = {}, a1 = {};
    if (active) {
        const float* row = hin + (size_t)(n0 + m) * 64 + quad * 8;
        float4 p0 = *(const float4*)(row);
        float4 p1 = *(const float4*)(row + 4);
        float4 p2 = *(const float4*)(row + 32);
        float4 p3 = *(const float4*)(row + 36);
        a0[0] = (_Float16)p0.x; a0[1] = (_Float16)p0.y; a0[2] = (_Float16)p0.z; a0[3] = (_Float16)p0.w;
        a0[4] = (_Float16)p1.x; a0[5] = (_Float16)p1.y; a0[6] = (_Float16)p1.z; a0[7] = (_Float16)p1.w;
        a1[0] = (_Float16)p2.x; a1[1] = (_Float16)p2.y; a1[2] = (_Float16)p2.z; a1[3] = (_Float16)p2.w;
        a1[4] = (_Float16)p3.x; a1[5] = (_Float16)p3.y; a1[6] = (_Float16)p3.z; a1[7] = (_Float16)p3.w;
    }
    gemm_core(a0, a1, Whl, dinv, u, wv, lane, n0, active, lds);
}

// layers 1,2: fp16 hb rows
__global__ __launch_bounds__(256) void gemm_mfma_kernel(const _Float16* __restrict__ hin,
                                                        const _Float16* __restrict__ Whl,
                                                        const float* __restrict__ dinv,
                                                        _Float16* __restrict__ u) {
    __shared__ _Float16 lds[4][4][16][16];  // 8KB
    int wv = threadIdx.x >> 6;
    int wid = blockIdx.x * 4 + wv;
    int lane = threadIdx.x & 63;
    int m = lane & 15;
    int quad = lane >> 4;
    bool active = (wid < NN / 16);
    int n0 = wid * 16;
    f16x8 a0 = {}, a1 = {};
    if (active) {
        a0 = *(const f16x8*)(hin + (size_t)(n0 + m) * 64 + quad * 8);
        a1 = *(const f16x8*)(hin + (size_t)(n0 + m) * 64 + 32 + quad * 8);
    }
    gemm_core(a0, a1, Whl, dinv, u, wv, lane, n0, active, lds);
}

// ---- push-scatter aggregation ----
// Block = one (bucket, quarter). acc[256][17] f32 in LDS (stride 17 breaks the
// 16-way bank aliasing of stride-16). 2 lanes/edge (fl = 8-feature half),
// depth-4 unrolled edge stream: uniform loop bounds -> no divergence, 4
// independent u-loads in flight per lane.

__device__ __forceinline__ void atomadd8(float* __restrict__ ap, float4 raw) {
    const __half2* h = (const __half2*)&raw;
#pragma unroll
    for (int k = 0; k < 4; k++) {
        float2 f = __half22float2(h[k]);
        atomicAdd(ap + 2 * k, f.x);
        atomicAdd(ap + 2 * k + 1, f.y);
    }
}

__device__ __forceinline__ void push_edges(const __half* __restrict__ uq,
                                           const int* __restrict__ pairs,
                                           float (*acc)[17],
                                           int e0, int e1, int tid) {
    int i0 = tid >> 1;
    int fl = tid & 1;
    int e = e0 + i0;
    for (; e + 384 < e1; e += 512) {
        int p0 = pairs[e];
        int p1 = pairs[e + 128];
        int p2 = pairs[e + 256];
        int p3 = pairs[e + 384];
        float4 r0 = *(const float4*)(uq + (size_t)(p0 >> 8) * 16 + fl * 8);
        float4 r1 = *(const float4*)(uq + (size_t)(p1 >> 8) * 16 + fl * 8);
        float4 r2 = *(const float4*)(uq + (size_t)(p2 >> 8) * 16 + fl * 8);
        float4 r3 = *(const float4*)(uq + (size_t)(p3 >> 8) * 16 + fl * 8);
        atomadd8(&acc[p0 & 255][fl * 8], r0);
        atomadd8(&acc[p1 & 255][fl * 8], r1);
        atomadd8(&acc[p2 & 255][fl * 8], r2);
        atomadd8(&acc[p3 & 255][fl * 8], r3);
    }
    for (; e < e1; e += 128) {
        int p = pairs[e];
        float4 r = *(const float4*)(uq + (size_t)(p >> 8) * 16 + fl * 8);
        atomadd8(&acc[p & 255][fl * 8], r);
    }
}

// self-term init: thread tid owns node n0+tid, loads its own u quarter row
__device__ __forceinline__ void self_init(const __half* __restrict__ uq,
                                          float (*acc)[17], int n, int tid) {
    if (n < NN) {
        float4 s0 = *(const float4*)(uq + (size_t)n * 16);
        float4 s1 = *(const float4*)(uq + (size_t)n * 16 + 8);
        const __half2* h0 = (const __half2*)&s0;
        const __half2* h1 = (const __half2*)&s1;
#pragma unroll
        for (int k = 0; k < 4; k++) {
            float2 f = __half22float2(h0[k]);
            acc[tid][2 * k] = f.x;
            acc[tid][2 * k + 1] = f.y;
        }
#pragma unroll
        for (int k = 0; k < 4; k++) {
            float2 f = __half22float2(h1[k]);
            acc[tid][8 + 2 * k] = f.x;
            acc[tid][9 + 2 * k] = f.y;
        }
    } else {
#pragma unroll
        for (int j = 0; j < 16; j++) acc[tid][j] = 0.f;
    }
}

// layers 0,1: scatter + relu/bias epilogue -> fp16 hb
__global__ __launch_bounds__(256) void pushagg_kernel(const __half* __restrict__ u,
                                                      const int* __restrict__ pairs,
                                                      const int* __restrict__ bcur,
                                                      const float* __restrict__ dinv,
                                                      const float* __restrict__ bias,
                                                      __half* __restrict__ hout) {
    int q = blockIdx.x & 3;
    int b = blockIdx.x >> 2;
    int tid = threadIdx.x;
    int n = (b << 8) + tid;
    const __half* uq = u + (size_t)q * NN * 16;
    __shared__ float acc[256][17];
    self_init(uq, acc, n, tid);
    __syncthreads();
    int e0 = b * CAP;
    push_edges(uq, pairs, acc, e0, e0 + bcur[b], tid);
    __syncthreads();
    if (n < NN) {
        float dv = dinv[n];
        const float* bq = bias + q * 16;
        __half2 hh[8];
#pragma unroll
        for (int k = 0; k < 8; k++) {
            float x0 = fmaxf(fmaf(dv, acc[tid][2 * k], bq[2 * k]), 0.f);
            float x1 = fmaxf(fmaf(dv, acc[tid][2 * k + 1], bq[2 * k + 1]), 0.f);
            hh[k] = __floats2half2_rn(x0, x1);
        }
        *(float4*)(hout + (size_t)n * 64 + q * 16) = *(float4*)&hh[0];
        *(float4*)(hout + (size_t)n * 64 + q * 16 + 8) = *(float4*)&hh[4];
    }
}

// layer 2: scatter + relu/bias + fused segmented mean-pool partials (batch sorted)
__global__ __launch_bounds__(256) void pushagg_pool_kernel(const __half* __restrict__ u,
                                                           const int* __restrict__ pairs,
                                                           const int* __restrict__ bcur,
                                                           const float* __restrict__ dinv,
                                                           const float* __restrict__ bias,
                                                           const int* __restrict__ batch,
                                                           float* __restrict__ gsum) {
    int q = blockIdx.x & 3;
    int b = blockIdx.x >> 2;
    int tid = threadIdx.x;
    int n = (b << 8) + tid;
    const __half* uq = u + (size_t)q * NN * 16;
    __shared__ float acc[256][17];
    __shared__ int sg[256];
    self_init(uq, acc, n, tid);
    sg[tid] = (n < NN) ? batch[n] : (GG - 1);
    __syncthreads();
    int e0 = b * CAP;
    push_edges(uq, pairs, acc, e0, e0 + bcur[b], tid);
    __syncthreads();
    // relu(dinv*acc + b) written back in-place (own row only)
    {
        bool nv = (n < NN);
        float dv = nv ? dinv[n] : 0.f;
        const float* bq = bias + q * 16;
#pragma unroll
        for (int j = 0; j < 16; j++) {
            float r = nv ? fmaxf(fmaf(dv, acc[tid][j], bq[j]), 0.f) : 0.f;
            acc[tid][j] = r;
        }
    }
    __syncthreads();
    // segmented run-sum over sorted batch ids: 8 chunks x 16 features
    if (tid < 128) {
        int c = tid >> 4;
        int j = tid & 15;
        int base = c << 5;
        float run = acc[base][j];
        int curg = sg[base];
        for (int i = 1; i < 32; i++) {
            int g = sg[base + i];
            if (g != curg) {
                atomicAdd(&gsum[curg * 64 + q * 16 + j], run);
                run = 0.f;
                curg = g;
            }
            run += acc[base + i][j];
        }
        atomicAdd(&gsum[curg * 64 + q * 16 + j], run);
    }
}

__global__ __launch_bounds__(128) void final_kernel(const float* __restrict__ gsum,
                                                    const float* __restrict__ gcnt,
                                                    const float* __restrict__ Wlin,
                                                    const float* __restrict__ blin,
                                                    float* __restrict__ out) {
    int t = threadIdx.x;  // 128 = G*C
    int g = t >> 1;
    int c = t & 1;
    float cnt = fmaxf(gcnt[g], 1.0f);
    float s = 0.0f;
#pragma unroll
    for (int k = 0; k < 64; k++) s = fmaf(gsum[g * 64 + k], Wlin[k * 2 + c], s);
    out[t] = s / cnt + blin[c];
}

extern "C" void kernel_launch(void* const* d_in, const int* in_sizes, int n_in,
                              void* d_out, int out_size, void* d_ws, size_t ws_size,
                              hipStream_t stream) {
    const float* x     = (const float*)d_in[0];
    const int*   ei    = (const int*)d_in[1];
    const int*   batch = (const int*)d_in[2];
    const float* W0    = (const float*)d_in[3];
    const float* b0    = (const float*)d_in[4];
    const float* W1    = (const float*)d_in[5];
    const float* b1    = (const float*)d_in[6];
    const float* W2    = (const float*)d_in[7];
    const float* b2    = (const float*)d_in[8];
    const float* Wlin  = (const float*)d_in[9];
    const float* blin  = (const float*)d_in[10];
    float* out = (float*)d_out;

    char* ws = (char*)d_ws;
    float*    dinv     = (float*)(ws + 800000);
    int*      pairs    = (int*)(ws + 1200000);       // 12812288 B, ends 14012288
    __half*   u        = (__half*)(ws + 14012288);   // ends 26812288
    __half*   hb       = (__half*)(ws + 26812288);   // ends 39612288
    _Float16* Wh       = (_Float16*)(ws + 52424576); // 3 x 32768 B, ends 52522880
    float*    gsum     = (float*)(ws + 52522880);
    float*    gcnt     = (float*)(ws + 52539264);
    int*      bcur     = (int*)(ws + 52539520);

    // zero gsum+gcnt+bcur (contiguous)
    hipMemsetAsync(ws + 52522880, 0, 18204, stream);

    // bucket-scatter pairs, per-bucket degree histogram -> dinv, merged prep
    bplace_kernel<<<cdiv_h(EE, 4096), 256, 0, stream>>>(ei, bcur, pairs);
    bdeg_kernel<<<NBK, 256, 0, stream>>>(pairs, bcur, dinv);
    prep_kernel<<<3 + cdiv_h(NN, 256), 256, 0, stream>>>(W0, W1, W2, Wh, batch, gcnt);

    int gemm_blocks = cdiv_h(NN / 16, 4);    // 6250 waves, 16 rows, all quarters
    int agg_blocks = NBK * 4;                // 391 buckets x 4 quarters

    gemm_mfma_f32_kernel<<<gemm_blocks, 256, 0, stream>>>(x, Wh, dinv, (_Float16*)u);
    pushagg_kernel<<<agg_blocks, 256, 0, stream>>>(u, pairs, bcur, dinv, b0, hb);
    gemm_mfma_kernel<<<gemm_blocks, 256, 0, stream>>>((const _Float16*)hb, Wh + 16384, dinv, (_Float16*)u);
    pushagg_kernel<<<agg_blocks, 256, 0, stream>>>(u, pairs, bcur, dinv, b1, hb);
    gemm_mfma_kernel<<<gemm_blocks, 256, 0, stream>>>((const _Float16*)hb, Wh + 32768, dinv, (_Float16*)u);
    pushagg_pool_kernel<<<agg_blocks, 256, 0, stream>>>(u, pairs, bcur, dinv, b2, batch, gsum);

    final_kernel<<<1, 128, 0, stream>>>(gsum, gcnt, Wlin, blin, out);
}

// Round 5
// 370.571 us; speedup vs baseline: 5.2449x; 5.2449x over previous
//
#include <hip/hip_runtime.h>
#include <hip/hip_fp16.h>

#define NN 100000
#define EE 1600000
#define HH 64
#define GG 64
#define NBK 391    // buckets of 256 nodes: dst>>8
#define CAP 8192   // fixed bucket capacity (mean load 4092, max ~4400)

typedef _Float16 f16x8 __attribute__((ext_vector_type(8)));
typedef float f32x4 __attribute__((ext_vector_type(4)));

// ---------------- workspace layout (bytes) ----------------
// rowStart : int[NN]          @ 0
// rowLen   : int[NN]          @ 400000
// dinv     : float[NN]        @ 800000
// srcs     : int[NBK*CAP]     @ 1200000   (ends 14012288)
// u        : half[NN][64]     @ 14012288  (ends 26812288)  -- row-major, 128B rows
// hb(half) : half[NN*64]      @ 26812288  (ends 39612288)
// tmp      : int[NBK*CAP]     @ 26812288  (overlaps hb; dead after bsort)
// perm     : int[NBK*256]     @ 39612288  (ends 40012672)  degree-sorted node order
// Wh       : half[3][16384]   @ 52424576  (32KB/layer, ends 52522880)
// gsum     : float[4096]      @ 52522880
// gcnt     : float[64]        @ 52539264
// bcur     : int[NBK]         @ 52539520
//
// Failed-experiment ledger (keep!):
//  R8  col-split gemm: VALUBusy 6.8%, 2x slower (halved ILP per row-read)
//  R13 producer-local gemm: agg FETCH unchanged (L2 invalidated at dispatch edge)
//  R15 warm_slice + nt hints: agg 46->69us, FETCH 31->41MB (nt evicts srcs)
//  R17 fp32 eighth-tables: VALU 43->29% but bytes/edge 2x -> agg 46->83us
//  R18 PUSH-scatter (LDS ds_add_f32 per edge): 598us/pass, VALUBusy 1.1%,
//      388K bank-conflict cycles; LDS atomic pipe serializes. NEVER retry
//      raw LDS-atomic scatter at 16 atomics/edge.
//  PROCESS: one fenced block per response, first fence in the response,
//      and no backtick characters anywhere else (prose or comments).
//  => pull gather is the structure; R19 = merged row table (full 128B line
//     use, 4 loads in flight) + degree-sorted perm (kills max-of-8 divergence).

static inline int cdiv_h(int a, int b) { return (a + b - 1) / b; }

// ---- partition edges into fixed-capacity buckets (391 blocks x 4096 edges) ----
__global__ __launch_bounds__(256) void bplace_kernel(const int* __restrict__ ei,
                                                     int* __restrict__ bcur,
                                                     int* __restrict__ tmp) {
    __shared__ int h[NBK];
    __shared__ int boff[NBK];
    for (int t = threadIdx.x; t < NBK; t += 256) h[t] = 0;
    __syncthreads();
    int base = blockIdx.x * 4096;
#pragma unroll 4
    for (int i = 0; i < 16; i++) {
        int e = base + i * 256 + threadIdx.x;
        if (e < EE) atomicAdd(&h[ei[EE + e] >> 8], 1);
    }
    __syncthreads();
    for (int t = threadIdx.x; t < NBK; t += 256) {
        int c = h[t];
        boff[t] = c ? (t * CAP + atomicAdd(&bcur[t], c)) : 0;
        h[t] = 0;  // reuse as running cursor
    }
    __syncthreads();
#pragma unroll 4
    for (int i = 0; i < 16; i++) {
        int e = base + i * 256 + threadIdx.x;
        if (e < EE) {
            int s0 = ei[e];
            int d = ei[EE + e];
            int b = d >> 8;
            int p = boff[b] + atomicAdd(&h[b], 1);
            tmp[p] = (s0 << 8) | (d & 255);
        }
    }
}

// ---- per-bucket counting sort + degree-sorted perm ----
__global__ __launch_bounds__(256) void bsort_kernel(const int* __restrict__ tmp,
                                                    const int* __restrict__ bcur,
                                                    int* __restrict__ rowStart,
                                                    int* __restrict__ rowLen,
                                                    float* __restrict__ dinv,
                                                    int* __restrict__ srcs,
                                                    int* __restrict__ perm) {
    int b = blockIdx.x;
    int n0 = b << 8;
    int e0 = b * CAP;
    int e1 = e0 + bcur[b];
    int t = threadIdx.x;
    __shared__ int cnt[256];
    __shared__ int st[256];
    __shared__ int dh[64];
    __shared__ int dcur[64];
    cnt[t] = 0;
    if (t < 64) dh[t] = 0;
    __syncthreads();
    for (int e = e0 + t; e < e1; e += 256) atomicAdd(&cnt[tmp[e] & 255], 1);
    __syncthreads();
    int v = cnt[t];
    st[t] = v;
    __syncthreads();
    for (int off = 1; off < 256; off <<= 1) {
        int w = (t >= off) ? st[t - off] : 0;
        __syncthreads();
        st[t] += w;
        __syncthreads();
    }
    int excl = st[t] - v;
    int n = n0 + t;
    if (n < NN) {
        rowStart[n] = e0 + excl;
        rowLen[n] = v;
        dinv[n] = rsqrtf((float)v + 1.0f);
    }
    // degree-sorted permutation of this bucket's 256 slots
    int bin = (v > 63) ? 63 : v;
    atomicAdd(&dh[bin], 1);
    __syncthreads();
    if (t == 0) {
        int s = 0;
        for (int i = 0; i < 64; i++) { int c = dh[i]; dcur[i] = s; s += c; }
    }
    __syncthreads();
    int rank = atomicAdd(&dcur[bin], 1);
    perm[n0 + rank] = n;  // may be >= NN for pad slots of last bucket
    __syncthreads();
    cnt[t] = e0 + excl;  // absolute cursor
    __syncthreads();
    for (int e = e0 + t; e < e1; e += 256) {
        int p = tmp[e];
        int pos = atomicAdd(&cnt[p & 255], 1);
        srcs[pos] = p >> 8;
    }
}

// ---- merged prep: blocks 0-2 = W swizzle (hi/lo B-frags); blocks 3+ = gcnt ----
__global__ __launch_bounds__(256) void prep_kernel(const float* __restrict__ W0,
                                                   const float* __restrict__ W1,
                                                   const float* __restrict__ W2,
                                                   _Float16* __restrict__ Wh,
                                                   const int* __restrict__ batch,
                                                   float* __restrict__ gcnt) {
    if (blockIdx.x < 3) {
        const float* Wl = (blockIdx.x == 0) ? W0 : (blockIdx.x == 1) ? W1 : W2;
        _Float16* out = Wh + blockIdx.x * 16384;
        for (int c = threadIdx.x; c < 512; c += 256) {  // t(4) x h(2) x lane(64)
            int t = c >> 7;
            int h = (c >> 6) & 1;
            int lane = c & 63;
            int quad = lane >> 4;
            int n = lane & 15;
#pragma unroll
            for (int j = 0; j < 8; j++) {
                int k = h * 32 + quad * 8 + j;
                float w = Wl[k * 64 + t * 16 + n];
                _Float16 hi = (_Float16)w;
                _Float16 lo = (_Float16)(w - (float)hi);
                out[(((t * 2 + h) * 2 + 0) * 64 + lane) * 8 + j] = hi;
                out[(((t * 2 + h) * 2 + 1) * 64 + lane) * 8 + j] = lo;
            }
        }
    } else {
        __shared__ int h[GG];
        if (threadIdx.x < GG) h[threadIdx.x] = 0;
        __syncthreads();
        int n = (blockIdx.x - 3) * 256 + threadIdx.x;
        if (n < NN) atomicAdd(&h[batch[n]], 1);
        __syncthreads();
        if (threadIdx.x < GG && h[threadIdx.x])
            atomicAdd(&gcnt[threadIdx.x], (float)h[threadIdx.x]);
    }
}

// ---- MFMA gemm core (A frags in registers -> u row table via LDS) ----
__device__ __forceinline__ void gemm_core(f16x8 a0, f16x8 a1,
                                          const _Float16* __restrict__ Whl,
                                          const float* __restrict__ dinv,
                                          _Float16* __restrict__ u,
                                          int wv, int lane, int n0, bool active,
                                          _Float16 (*lds)[4][16][16]) {
    int m = lane & 15;
    int quad = lane >> 4;
    if (active) {
        f32x4 acc[4];
#pragma unroll
        for (int t = 0; t < 4; t++) acc[t] = (f32x4){0.f, 0.f, 0.f, 0.f};
#pragma unroll
        for (int t = 0; t < 4; t++) {
            f16x8 bh0 = *(const f16x8*)(Whl + (((t * 2 + 0) * 2 + 0) * 64 + lane) * 8);
            f16x8 bl0 = *(const f16x8*)(Whl + (((t * 2 + 0) * 2 + 1) * 64 + lane) * 8);
            f16x8 bh1 = *(const f16x8*)(Whl + (((t * 2 + 1) * 2 + 0) * 64 + lane) * 8);
            f16x8 bl1 = *(const f16x8*)(Whl + (((t * 2 + 1) * 2 + 1) * 64 + lane) * 8);
            acc[t] = __builtin_amdgcn_mfma_f32_16x16x32_f16(a0, bh0, acc[t], 0, 0, 0);
            acc[t] = __builtin_amdgcn_mfma_f32_16x16x32_f16(a0, bl0, acc[t], 0, 0, 0);
            acc[t] = __builtin_amdgcn_mfma_f32_16x16x32_f16(a1, bh1, acc[t], 0, 0, 0);
            acc[t] = __builtin_amdgcn_mfma_f32_16x16x32_f16(a1, bl1, acc[t], 0, 0, 0);
        }
        // D layout: col = lane&15 (= feature), row = quad*4 + reg (= node) [m89/m91]
        float4 dv4 = *(const float4*)(dinv + n0 + quad * 4);
        const float* dvp = (const float*)&dv4;
#pragma unroll
        for (int t = 0; t < 4; t++)
#pragma unroll
            for (int i = 0; i < 4; i++)
                lds[wv][t][quad * 4 + i][m] = (_Float16)(acc[t][i] * dvp[i]);
    }
    __syncthreads();
    if (active) {
        int t = lane >> 4;
        int node = lane & 15;
        f16x8 v0 = *(const f16x8*)&lds[wv][t][node][0];
        f16x8 v1 = *(const f16x8*)&lds[wv][t][node][8];
        _Float16* dst = u + ((size_t)(n0 + node)) * 64 + t * 16;  // row table
        *(f16x8*)dst = v0;
        *(f16x8*)(dst + 8) = v1;
    }
}

// layer 0: fp32 x rows, convert to A-frags in-register (no cast pass needed)
__global__ __launch_bounds__(256) void gemm_mfma_f32_kernel(const float* __restrict__ hin,
                                                            const _Float16* __restrict__ Whl,
                                                            const float* __restrict__ dinv,
                                                            _Float16* __restrict__ u) {
    __shared__ _Float16 lds[4][4][16][16];  // 8KB
    int wv = threadIdx.x >> 6;
    int wid = blockIdx.x * 4 + wv;
    int lane = threadIdx.x & 63;
    int m = lane & 15;
    int quad = lane >> 4;
    bool active = (wid < NN / 16);
    int n0 = wid * 16;
    f16x8 a0 = {}, a1 = {};
    if (active) {
        const float* row = hin + (size_t)(n0 + m) * 64 + quad * 8;
        float4 p0 = *(const float4*)(row);
        float4 p1 = *(const float4*)(row + 4);
        float4 p2 = *(const float4*)(row + 32);
        float4 p3 = *(const float4*)(row + 36);
        a0[0] = (_Float16)p0.x; a0[1] = (_Float16)p0.y; a0[2] = (_Float16)p0.z; a0[3] = (_Float16)p0.w;
        a0[4] = (_Float16)p1.x; a0[5] = (_Float16)p1.y; a0[6] = (_Float16)p1.z; a0[7] = (_Float16)p1.w;
        a1[0] = (_Float16)p2.x; a1[1] = (_Float16)p2.y; a1[2] = (_Float16)p2.z; a1[3] = (_Float16)p2.w;
        a1[4] = (_Float16)p3.x; a1[5] = (_Float16)p3.y; a1[6] = (_Float16)p3.z; a1[7] = (_Float16)p3.w;
    }
    gemm_core(a0, a1, Whl, dinv, u, wv, lane, n0, active, lds);
}

// layers 1,2: fp16 hb rows
__global__ __launch_bounds__(256) void gemm_mfma_kernel(const _Float16* __restrict__ hin,
                                                        const _Float16* __restrict__ Whl,
                                                        const float* __restrict__ dinv,
                                                        _Float16* __restrict__ u) {
    __shared__ _Float16 lds[4][4][16][16];  // 8KB
    int wv = threadIdx.x >> 6;
    int wid = blockIdx.x * 4 + wv;
    int lane = threadIdx.x & 63;
    int m = lane & 15;
    int quad = lane >> 4;
    bool active = (wid < NN / 16);
    int n0 = wid * 16;
    f16x8 a0 = {}, a1 = {};
    if (active) {
        a0 = *(const f16x8*)(hin + (size_t)(n0 + m) * 64 + quad * 8);
        a1 = *(const f16x8*)(hin + (size_t)(n0 + m) * 64 + 32 + quad * 8);
    }
    gemm_core(a0, a1, Whl, dinv, u, wv, lane, n0, active, lds);
}

// ---- full-row pull gather: 8 lanes/node (sub 0..3 x fl 0..1), 4x16B per edge ----
__device__ __forceinline__ void add8(float4 raw, float* a) {
    const __half2* h = (const __half2*)&raw;
#pragma unroll
    for (int i = 0; i < 4; i++) {
        float2 f = __half22float2(h[i]);
        a[2 * i] += f.x;
        a[2 * i + 1] += f.y;
    }
}

__device__ __forceinline__ void addrow(const __half* __restrict__ row, float* a) {
    float4 r0 = *(const float4*)(row);
    float4 r1 = *(const float4*)(row + 16);
    float4 r2 = *(const float4*)(row + 32);
    float4 r3 = *(const float4*)(row + 48);
    add8(r0, a);
    add8(r1, a + 8);
    add8(r2, a + 16);
    add8(r3, a + 24);
}

// unified agg: one block = 32 degree-sorted node slots, all 64 features.
// Each lane owns 32 features (fl half x 4 quarters); 4 x 16B loads per edge.
__global__ __launch_bounds__(256) void agg_kernel(const __half* __restrict__ u,
                                                  const int* __restrict__ srcs,
                                                  const int* __restrict__ rowStart,
                                                  const int* __restrict__ rowLen,
                                                  const float* __restrict__ dinv,
                                                  const int* __restrict__ perm,
                                                  const float* __restrict__ bias,
                                                  __half* __restrict__ hout) {
    int grp = blockIdx.x;
    int w = threadIdx.x >> 6;
    int lane = threadIdx.x & 63;
    int ng = lane >> 3;
    int sub = (lane >> 1) & 3;
    int fl = lane & 1;
    int slot = grp * 32 + w * 8 + ng;
    int n = perm[slot];
    bool valid = (n < NN);
    int rs = 0, len = 0;
    if (valid) { rs = rowStart[n]; len = rowLen[n]; }
    const __half* ub = u + (size_t)fl * 8;
    float a[32];
#pragma unroll
    for (int i = 0; i < 32; i++) a[i] = 0.0f;
    if (valid && sub == 0) addrow(ub + (size_t)n * 64, a);  // self term
    int e = rs + sub, end = rs + len;
    for (; e + 4 < end; e += 8) {
        int sA = srcs[e];
        int sB = srcs[e + 4];
        const __half* ra = ub + (size_t)sA * 64;
        const __half* rb = ub + (size_t)sB * 64;
        float4 a0 = *(const float4*)(ra);
        float4 a1 = *(const float4*)(ra + 16);
        float4 a2 = *(const float4*)(ra + 32);
        float4 a3 = *(const float4*)(ra + 48);
        float4 b0 = *(const float4*)(rb);
        float4 b1 = *(const float4*)(rb + 16);
        float4 b2 = *(const float4*)(rb + 32);
        float4 b3 = *(const float4*)(rb + 48);
        add8(a0, a);
        add8(a1, a + 8);
        add8(a2, a + 16);
        add8(a3, a + 24);
        add8(b0, a);
        add8(b1, a + 8);
        add8(b2, a + 16);
        add8(b3, a + 24);
    }
    if (e < end) addrow(ub + (size_t)srcs[e] * 64, a);
    // reduce across sub lanes (xor 2, 4)
#pragma unroll
    for (int m = 2; m <= 4; m <<= 1) {
#pragma unroll
        for (int i = 0; i < 32; i++) a[i] += __shfl_xor(a[i], m);
    }
    if (valid && sub == 0) {
        float dv = dinv[n];
#pragma unroll
        for (int q = 0; q < 4; q++) {
            const float4* bb = (const float4*)(bias + q * 16 + fl * 8);
            float4 b0 = bb[0], b1 = bb[1];
            float r[8];
            r[0] = fmaxf(fmaf(dv, a[q * 8 + 0], b0.x), 0.0f);
            r[1] = fmaxf(fmaf(dv, a[q * 8 + 1], b0.y), 0.0f);
            r[2] = fmaxf(fmaf(dv, a[q * 8 + 2], b0.z), 0.0f);
            r[3] = fmaxf(fmaf(dv, a[q * 8 + 3], b0.w), 0.0f);
            r[4] = fmaxf(fmaf(dv, a[q * 8 + 4], b1.x), 0.0f);
            r[5] = fmaxf(fmaf(dv, a[q * 8 + 5], b1.y), 0.0f);
            r[6] = fmaxf(fmaf(dv, a[q * 8 + 6], b1.z), 0.0f);
            r[7] = fmaxf(fmaf(dv, a[q * 8 + 7], b1.w), 0.0f);
            __half2 hh[4];
#pragma unroll
            for (int i = 0; i < 4; i++) hh[i] = __floats2half2_rn(r[2 * i], r[2 * i + 1]);
            *(float4*)(hout + (size_t)n * 64 + q * 16 + fl * 8) = *(float4*)hh;
        }
    }
}

// ---- mean-pool partial sums over natural node order (batch sorted) ----
__global__ __launch_bounds__(256) void pool_kernel(const __half* __restrict__ hb,
                                                   const int* __restrict__ batch,
                                                   float* __restrict__ gsum) {
    int b = blockIdx.x;           // bucket of 256 nodes
    int fg = threadIdx.x & 7;     // feature group (8 features)
    int chunk = threadIdx.x >> 3; // 32 chunks of 8 nodes
    int base = (b << 8) + chunk * 8;
    float r[8];
#pragma unroll
    for (int k = 0; k < 8; k++) r[k] = 0.0f;
    int cur = -1;
    for (int i = 0; i < 8; i++) {
        int n = base + i;
        if (n >= NN) break;
        int g = batch[n];
        if (g != cur) {
            if (cur >= 0) {
#pragma unroll
                for (int k = 0; k < 8; k++) atomicAdd(&gsum[cur * 64 + fg * 8 + k], r[k]);
#pragma unroll
                for (int k = 0; k < 8; k++) r[k] = 0.0f;
            }
            cur = g;
        }
        add8(*(const float4*)(hb + (size_t)n * 64 + fg * 8), r);
    }
    if (cur >= 0) {
#pragma unroll
        for (int k = 0; k < 8; k++) atomicAdd(&gsum[cur * 64 + fg * 8 + k], r[k]);
    }
}

__global__ __launch_bounds__(128) void final_kernel(const float* __restrict__ gsum,
                                                    const float* __restrict__ gcnt,
                                                    const float* __restrict__ Wlin,
                                                    const float* __restrict__ blin,
                                                    float* __restrict__ out) {
    int t = threadIdx.x;  // 128 = G*C
    int g = t >> 1;
    int c = t & 1;
    float cnt = fmaxf(gcnt[g], 1.0f);
    float s = 0.0f;
#pragma unroll
    for (int k = 0; k < 64; k++) s = fmaf(gsum[g * 64 + k], Wlin[k * 2 + c], s);
    out[t] = s / cnt + blin[c];
}

extern "C" void kernel_launch(void* const* d_in, const int* in_sizes, int n_in,
                              void* d_out, int out_size, void* d_ws, size_t ws_size,
                              hipStream_t stream) {
    const float* x     = (const float*)d_in[0];
    const int*   ei    = (const int*)d_in[1];
    const int*   batch = (const int*)d_in[2];
    const float* W0    = (const float*)d_in[3];
    const float* b0    = (const float*)d_in[4];
    const float* W1    = (const float*)d_in[5];
    const float* b1    = (const float*)d_in[6];
    const float* W2    = (const float*)d_in[7];
    const float* b2    = (const float*)d_in[8];
    const float* Wlin  = (const float*)d_in[9];
    const float* blin  = (const float*)d_in[10];
    float* out = (float*)d_out;

    char* ws = (char*)d_ws;
    int*      rowStart = (int*)(ws + 0);
    int*      rowLen   = (int*)(ws + 400000);
    float*    dinv     = (float*)(ws + 800000);
    int*      srcs     = (int*)(ws + 1200000);
    __half*   u        = (__half*)(ws + 14012288);
    __half*   hb       = (__half*)(ws + 26812288);
    int*      tmp      = (int*)(ws + 26812288);   // overlaps hb; dead after bsort
    int*      perm     = (int*)(ws + 39612288);   // 400384 B, ends 40012672
    _Float16* Wh       = (_Float16*)(ws + 52424576);  // 3 x 32768 B, ends 52522880
    float*    gsum     = (float*)(ws + 52522880);
    float*    gcnt     = (float*)(ws + 52539264);
    int*      bcur     = (int*)(ws + 52539520);

    // zero gsum+gcnt+bcur (contiguous)
    hipMemsetAsync(ws + 52522880, 0, 18204, stream);

    // CSR build (+ degree-sorted perm), then merged prep (W swizzle + gcnt)
    bplace_kernel<<<cdiv_h(EE, 4096), 256, 0, stream>>>(ei, bcur, tmp);
    bsort_kernel<<<NBK, 256, 0, stream>>>(tmp, bcur, rowStart, rowLen, dinv, srcs, perm);
    prep_kernel<<<3 + cdiv_h(NN, 256), 256, 0, stream>>>(W0, W1, W2, Wh, batch, gcnt);

    int gemm_blocks = cdiv_h(NN / 16, 4);    // 6250 waves, 16 rows each
    int agg_blocks = NBK * 8;                // 3128 blocks x 32 slots

    gemm_mfma_f32_kernel<<<gemm_blocks, 256, 0, stream>>>(x, Wh, dinv, (_Float16*)u);
    agg_kernel<<<agg_blocks, 256, 0, stream>>>(u, srcs, rowStart, rowLen, dinv, perm, b0, hb);
    gemm_mfma_kernel<<<gemm_blocks, 256, 0, stream>>>((const _Float16*)hb, Wh + 16384, dinv, (_Float16*)u);
    agg_kernel<<<agg_blocks, 256, 0, stream>>>(u, srcs, rowStart, rowLen, dinv, perm, b1, hb);
    gemm_mfma_kernel<<<gemm_blocks, 256, 0, stream>>>((const _Float16*)hb, Wh + 32768, dinv, (_Float16*)u);
    agg_kernel<<<agg_blocks, 256, 0, stream>>>(u, srcs, rowStart, rowLen, dinv, perm, b2, hb);
    pool_kernel<<<NBK, 256, 0, stream>>>(hb, batch, gsum);

    final_kernel<<<1, 128, 0, stream>>>(gsum, gcnt, Wlin, blin, out);
}

// Round 6
// 309.597 us; speedup vs baseline: 6.2779x; 1.1969x over previous
//
#include <hip/hip_runtime.h>
#include <hip/hip_fp16.h>

#define NN 100000
#define EE 1600000
#define HH 64
#define GG 64
#define NBK 391    // buckets of 256 nodes: dst>>8
#define CAP 8192   // fixed bucket capacity (mean load 4092, max ~4400)

typedef _Float16 f16x8 __attribute__((ext_vector_type(8)));
typedef float f32x4 __attribute__((ext_vector_type(4)));

// ---------------- workspace layout (bytes) ----------------
// rowStart : int[NN]          @ 0
// rowLen   : int[NN]          @ 400000
// dinv     : float[NN]        @ 800000
// srcs     : int[NBK*CAP]     @ 1200000   (ends 14012288)
// u        : half[NN][64]     @ 14012288  (ends 26812288)  -- row-major, 128B rows
// hb(half) : half[NN*64]      @ 26812288  (ends 39612288)
// tmp      : int[NBK*CAP]     @ 26812288  (overlaps hb; dead after bsort)
// perm     : int[NBK*256]     @ 39612288  (ends 40012672)  degree-sorted node order
// Wh       : half[3][16384]   @ 52424576  (32KB/layer, ends 52522880)
// gsum     : float[4096]      @ 52522880
// gcnt     : float[64]        @ 52539264
// bcur     : int[NBK]         @ 52539520
//
// Failed-experiment ledger (keep!):
//  R8  col-split gemm: VALUBusy 6.8%, 2x slower (halved ILP per row-read)
//  R13 producer-local gemm: agg FETCH unchanged (L2 invalidated at dispatch edge)
//  R15 warm_slice + nt hints: agg 46->69us, FETCH 31->41MB (nt evicts srcs)
//  R17 fp32 eighth-tables: VALU 43->29% but bytes/edge 2x -> agg 46->83us
//  R18 PUSH-scatter (LDS ds_add_f32 per edge): 598us/pass, VALUBusy 1.1%,
//      388K bank-conflict cycles; LDS atomic pipe serializes. NEVER retry
//      raw LDS-atomic scatter at 16 atomics/edge.
//  R19 naive pool (per-thread global atomic flush): 78us, WRITE 25.7MB for a
//      16KB output, VALUBusy 0.5% -- 1.5M device atomics on 4096 addrs
//      serialize at L2. Pre-aggregate per block before global atomics.
//  PROCESS: one fenced block per response, first fence in the response,
//      and no backtick characters anywhere else (prose or comments).
//  => pull gather is the structure; R19 agg = merged row table + degree-sorted
//     perm (agg counters pending, masked by pool in top-5).

static inline int cdiv_h(int a, int b) { return (a + b - 1) / b; }

// ---- partition edges into fixed-capacity buckets (391 blocks x 4096 edges) ----
__global__ __launch_bounds__(256) void bplace_kernel(const int* __restrict__ ei,
                                                     int* __restrict__ bcur,
                                                     int* __restrict__ tmp) {
    __shared__ int h[NBK];
    __shared__ int boff[NBK];
    for (int t = threadIdx.x; t < NBK; t += 256) h[t] = 0;
    __syncthreads();
    int base = blockIdx.x * 4096;
#pragma unroll 4
    for (int i = 0; i < 16; i++) {
        int e = base + i * 256 + threadIdx.x;
        if (e < EE) atomicAdd(&h[ei[EE + e] >> 8], 1);
    }
    __syncthreads();
    for (int t = threadIdx.x; t < NBK; t += 256) {
        int c = h[t];
        boff[t] = c ? (t * CAP + atomicAdd(&bcur[t], c)) : 0;
        h[t] = 0;  // reuse as running cursor
    }
    __syncthreads();
#pragma unroll 4
    for (int i = 0; i < 16; i++) {
        int e = base + i * 256 + threadIdx.x;
        if (e < EE) {
            int s0 = ei[e];
            int d = ei[EE + e];
            int b = d >> 8;
            int p = boff[b] + atomicAdd(&h[b], 1);
            tmp[p] = (s0 << 8) | (d & 255);
        }
    }
}

// ---- per-bucket counting sort + degree-sorted perm ----
__global__ __launch_bounds__(256) void bsort_kernel(const int* __restrict__ tmp,
                                                    const int* __restrict__ bcur,
                                                    int* __restrict__ rowStart,
                                                    int* __restrict__ rowLen,
                                                    float* __restrict__ dinv,
                                                    int* __restrict__ srcs,
                                                    int* __restrict__ perm) {
    int b = blockIdx.x;
    int n0 = b << 8;
    int e0 = b * CAP;
    int e1 = e0 + bcur[b];
    int t = threadIdx.x;
    __shared__ int cnt[256];
    __shared__ int st[256];
    __shared__ int dh[64];
    __shared__ int dcur[64];
    cnt[t] = 0;
    if (t < 64) dh[t] = 0;
    __syncthreads();
    for (int e = e0 + t; e < e1; e += 256) atomicAdd(&cnt[tmp[e] & 255], 1);
    __syncthreads();
    int v = cnt[t];
    st[t] = v;
    __syncthreads();
    for (int off = 1; off < 256; off <<= 1) {
        int w = (t >= off) ? st[t - off] : 0;
        __syncthreads();
        st[t] += w;
        __syncthreads();
    }
    int excl = st[t] - v;
    int n = n0 + t;
    if (n < NN) {
        rowStart[n] = e0 + excl;
        rowLen[n] = v;
        dinv[n] = rsqrtf((float)v + 1.0f);
    }
    // degree-sorted permutation of this bucket's 256 slots
    int bin = (v > 63) ? 63 : v;
    atomicAdd(&dh[bin], 1);
    __syncthreads();
    if (t == 0) {
        int s = 0;
        for (int i = 0; i < 64; i++) { int c = dh[i]; dcur[i] = s; s += c; }
    }
    __syncthreads();
    int rank = atomicAdd(&dcur[bin], 1);
    perm[n0 + rank] = n;  // may be >= NN for pad slots of last bucket
    __syncthreads();
    cnt[t] = e0 + excl;  // absolute cursor
    __syncthreads();
    for (int e = e0 + t; e < e1; e += 256) {
        int p = tmp[e];
        int pos = atomicAdd(&cnt[p & 255], 1);
        srcs[pos] = p >> 8;
    }
}

// ---- merged prep: blocks 0-2 = W swizzle (hi/lo B-frags); blocks 3+ = gcnt ----
__global__ __launch_bounds__(256) void prep_kernel(const float* __restrict__ W0,
                                                   const float* __restrict__ W1,
                                                   const float* __restrict__ W2,
                                                   _Float16* __restrict__ Wh,
                                                   const int* __restrict__ batch,
                                                   float* __restrict__ gcnt) {
    if (blockIdx.x < 3) {
        const float* Wl = (blockIdx.x == 0) ? W0 : (blockIdx.x == 1) ? W1 : W2;
        _Float16* out = Wh + blockIdx.x * 16384;
        for (int c = threadIdx.x; c < 512; c += 256) {  // t(4) x h(2) x lane(64)
            int t = c >> 7;
            int h = (c >> 6) & 1;
            int lane = c & 63;
            int quad = lane >> 4;
            int n = lane & 15;
#pragma unroll
            for (int j = 0; j < 8; j++) {
                int k = h * 32 + quad * 8 + j;
                float w = Wl[k * 64 + t * 16 + n];
                _Float16 hi = (_Float16)w;
                _Float16 lo = (_Float16)(w - (float)hi);
                out[(((t * 2 + h) * 2 + 0) * 64 + lane) * 8 + j] = hi;
                out[(((t * 2 + h) * 2 + 1) * 64 + lane) * 8 + j] = lo;
            }
        }
    } else {
        __shared__ int h[GG];
        if (threadIdx.x < GG) h[threadIdx.x] = 0;
        __syncthreads();
        int n = (blockIdx.x - 3) * 256 + threadIdx.x;
        if (n < NN) atomicAdd(&h[batch[n]], 1);
        __syncthreads();
        if (threadIdx.x < GG && h[threadIdx.x])
            atomicAdd(&gcnt[threadIdx.x], (float)h[threadIdx.x]);
    }
}

// ---- MFMA gemm core (A frags in registers -> u row table via LDS) ----
__device__ __forceinline__ void gemm_core(f16x8 a0, f16x8 a1,
                                          const _Float16* __restrict__ Whl,
                                          const float* __restrict__ dinv,
                                          _Float16* __restrict__ u,
                                          int wv, int lane, int n0, bool active,
                                          _Float16 (*lds)[4][16][16]) {
    int m = lane & 15;
    int quad = lane >> 4;
    if (active) {
        f32x4 acc[4];
#pragma unroll
        for (int t = 0; t < 4; t++) acc[t] = (f32x4){0.f, 0.f, 0.f, 0.f};
#pragma unroll
        for (int t = 0; t < 4; t++) {
            f16x8 bh0 = *(const f16x8*)(Whl + (((t * 2 + 0) * 2 + 0) * 64 + lane) * 8);
            f16x8 bl0 = *(const f16x8*)(Whl + (((t * 2 + 0) * 2 + 1) * 64 + lane) * 8);
            f16x8 bh1 = *(const f16x8*)(Whl + (((t * 2 + 1) * 2 + 0) * 64 + lane) * 8);
            f16x8 bl1 = *(const f16x8*)(Whl + (((t * 2 + 1) * 2 + 1) * 64 + lane) * 8);
            acc[t] = __builtin_amdgcn_mfma_f32_16x16x32_f16(a0, bh0, acc[t], 0, 0, 0);
            acc[t] = __builtin_amdgcn_mfma_f32_16x16x32_f16(a0, bl0, acc[t], 0, 0, 0);
            acc[t] = __builtin_amdgcn_mfma_f32_16x16x32_f16(a1, bh1, acc[t], 0, 0, 0);
            acc[t] = __builtin_amdgcn_mfma_f32_16x16x32_f16(a1, bl1, acc[t], 0, 0, 0);
        }
        // D layout: col = lane&15 (= feature), row = quad*4 + reg (= node) [m89/m91]
        float4 dv4 = *(const float4*)(dinv + n0 + quad * 4);
        const float* dvp = (const float*)&dv4;
#pragma unroll
        for (int t = 0; t < 4; t++)
#pragma unroll
            for (int i = 0; i < 4; i++)
                lds[wv][t][quad * 4 + i][m] = (_Float16)(acc[t][i] * dvp[i]);
    }
    __syncthreads();
    if (active) {
        int t = lane >> 4;
        int node = lane & 15;
        f16x8 v0 = *(const f16x8*)&lds[wv][t][node][0];
        f16x8 v1 = *(const f16x8*)&lds[wv][t][node][8];
        _Float16* dst = u + ((size_t)(n0 + node)) * 64 + t * 16;  // row table
        *(f16x8*)dst = v0;
        *(f16x8*)(dst + 8) = v1;
    }
}

// layer 0: fp32 x rows, convert to A-frags in-register (no cast pass needed)
__global__ __launch_bounds__(256) void gemm_mfma_f32_kernel(const float* __restrict__ hin,
                                                            const _Float16* __restrict__ Whl,
                                                            const float* __restrict__ dinv,
                                                            _Float16* __restrict__ u) {
    __shared__ _Float16 lds[4][4][16][16];  // 8KB
    int wv = threadIdx.x >> 6;
    int wid = blockIdx.x * 4 + wv;
    int lane = threadIdx.x & 63;
    int m = lane & 15;
    int quad = lane >> 4;
    bool active = (wid < NN / 16);
    int n0 = wid * 16;
    f16x8 a0 = {}, a1 = {};
    if (active) {
        const float* row = hin + (size_t)(n0 + m) * 64 + quad * 8;
        float4 p0 = *(const float4*)(row);
        float4 p1 = *(const float4*)(row + 4);
        float4 p2 = *(const float4*)(row + 32);
        float4 p3 = *(const float4*)(row + 36);
        a0[0] = (_Float16)p0.x; a0[1] = (_Float16)p0.y; a0[2] = (_Float16)p0.z; a0[3] = (_Float16)p0.w;
        a0[4] = (_Float16)p1.x; a0[5] = (_Float16)p1.y; a0[6] = (_Float16)p1.z; a0[7] = (_Float16)p1.w;
        a1[0] = (_Float16)p2.x; a1[1] = (_Float16)p2.y; a1[2] = (_Float16)p2.z; a1[3] = (_Float16)p2.w;
        a1[4] = (_Float16)p3.x; a1[5] = (_Float16)p3.y; a1[6] = (_Float16)p3.z; a1[7] = (_Float16)p3.w;
    }
    gemm_core(a0, a1, Whl, dinv, u, wv, lane, n0, active, lds);
}

// layers 1,2: fp16 hb rows
__global__ __launch_bounds__(256) void gemm_mfma_kernel(const _Float16* __restrict__ hin,
                                                        const _Float16* __restrict__ Whl,
                                                        const float* __restrict__ dinv,
                                                        _Float16* __restrict__ u) {
    __shared__ _Float16 lds[4][4][16][16];  // 8KB
    int wv = threadIdx.x >> 6;
    int wid = blockIdx.x * 4 + wv;
    int lane = threadIdx.x & 63;
    int m = lane & 15;
    int quad = lane >> 4;
    bool active = (wid < NN / 16);
    int n0 = wid * 16;
    f16x8 a0 = {}, a1 = {};
    if (active) {
        a0 = *(const f16x8*)(hin + (size_t)(n0 + m) * 64 + quad * 8);
        a1 = *(const f16x8*)(hin + (size_t)(n0 + m) * 64 + 32 + quad * 8);
    }
    gemm_core(a0, a1, Whl, dinv, u, wv, lane, n0, active, lds);
}

// ---- full-row pull gather: 8 lanes/node (sub 0..3 x fl 0..1), 4x16B per edge ----
__device__ __forceinline__ void add8(float4 raw, float* a) {
    const __half2* h = (const __half2*)&raw;
#pragma unroll
    for (int i = 0; i < 4; i++) {
        float2 f = __half22float2(h[i]);
        a[2 * i] += f.x;
        a[2 * i + 1] += f.y;
    }
}

__device__ __forceinline__ void addrow(const __half* __restrict__ row, float* a) {
    float4 r0 = *(const float4*)(row);
    float4 r1 = *(const float4*)(row + 16);
    float4 r2 = *(const float4*)(row + 32);
    float4 r3 = *(const float4*)(row + 48);
    add8(r0, a);
    add8(r1, a + 8);
    add8(r2, a + 16);
    add8(r3, a + 24);
}

// unified agg: one block = 32 degree-sorted node slots, all 64 features.
// Each lane owns 32 features (fl half x 4 quarters); 4 x 16B loads per edge.
__global__ __launch_bounds__(256) void agg_kernel(const __half* __restrict__ u,
                                                  const int* __restrict__ srcs,
                                                  const int* __restrict__ rowStart,
                                                  const int* __restrict__ rowLen,
                                                  const float* __restrict__ dinv,
                                                  const int* __restrict__ perm,
                                                  const float* __restrict__ bias,
                                                  __half* __restrict__ hout) {
    int grp = blockIdx.x;
    int w = threadIdx.x >> 6;
    int lane = threadIdx.x & 63;
    int ng = lane >> 3;
    int sub = (lane >> 1) & 3;
    int fl = lane & 1;
    int slot = grp * 32 + w * 8 + ng;
    int n = perm[slot];
    bool valid = (n < NN);
    int rs = 0, len = 0;
    if (valid) { rs = rowStart[n]; len = rowLen[n]; }
    const __half* ub = u + (size_t)fl * 8;
    float a[32];
#pragma unroll
    for (int i = 0; i < 32; i++) a[i] = 0.0f;
    if (valid && sub == 0) addrow(ub + (size_t)n * 64, a);  // self term
    int e = rs + sub, end = rs + len;
    for (; e + 4 < end; e += 8) {
        int sA = srcs[e];
        int sB = srcs[e + 4];
        const __half* ra = ub + (size_t)sA * 64;
        const __half* rb = ub + (size_t)sB * 64;
        float4 a0 = *(const float4*)(ra);
        float4 a1 = *(const float4*)(ra + 16);
        float4 a2 = *(const float4*)(ra + 32);
        float4 a3 = *(const float4*)(ra + 48);
        float4 b0 = *(const float4*)(rb);
        float4 b1 = *(const float4*)(rb + 16);
        float4 b2 = *(const float4*)(rb + 32);
        float4 b3 = *(const float4*)(rb + 48);
        add8(a0, a);
        add8(a1, a + 8);
        add8(a2, a + 16);
        add8(a3, a + 24);
        add8(b0, a);
        add8(b1, a + 8);
        add8(b2, a + 16);
        add8(b3, a + 24);
    }
    if (e < end) addrow(ub + (size_t)srcs[e] * 64, a);
    // reduce across sub lanes (xor 2, 4)
#pragma unroll
    for (int m = 2; m <= 4; m <<= 1) {
#pragma unroll
        for (int i = 0; i < 32; i++) a[i] += __shfl_xor(a[i], m);
    }
    if (valid && sub == 0) {
        float dv = dinv[n];
#pragma unroll
        for (int q = 0; q < 4; q++) {
            const float4* bb = (const float4*)(bias + q * 16 + fl * 8);
            float4 b0 = bb[0], b1 = bb[1];
            float r[8];
            r[0] = fmaxf(fmaf(dv, a[q * 8 + 0], b0.x), 0.0f);
            r[1] = fmaxf(fmaf(dv, a[q * 8 + 1], b0.y), 0.0f);
            r[2] = fmaxf(fmaf(dv, a[q * 8 + 2], b0.z), 0.0f);
            r[3] = fmaxf(fmaf(dv, a[q * 8 + 3], b0.w), 0.0f);
            r[4] = fmaxf(fmaf(dv, a[q * 8 + 4], b1.x), 0.0f);
            r[5] = fmaxf(fmaf(dv, a[q * 8 + 5], b1.y), 0.0f);
            r[6] = fmaxf(fmaf(dv, a[q * 8 + 6], b1.z), 0.0f);
            r[7] = fmaxf(fmaf(dv, a[q * 8 + 7], b1.w), 0.0f);
            __half2 hh[4];
#pragma unroll
            for (int i = 0; i < 4; i++) hh[i] = __floats2half2_rn(r[2 * i], r[2 * i + 1]);
            *(float4*)(hout + (size_t)n * 64 + q * 16 + fl * 8) = *(float4*)hh;
        }
    }
}

// ---- mean-pool: block = 128 contiguous nodes; LDS-binned pre-aggregation.
// batch is sorted, so a 128-node block spans ~2 graphs; bins are (g - gmin)
// with capacity 8 + direct-atomic fallback. Global atomics: ~128/block.
__global__ __launch_bounds__(256) void pool_kernel(const __half* __restrict__ hb,
                                                   const int* __restrict__ batch,
                                                   float* __restrict__ gsum) {
    int b = blockIdx.x;            // 782 blocks x 128 nodes
    int base = b << 7;
    int tid = threadIdx.x;
    int chunk = tid >> 3;          // 0..31, 4 nodes each
    int fg = tid & 7;              // feature group (8 features)
    __shared__ float lbin[8][64];
    __shared__ int sgmin;
    ((float*)lbin)[tid] = 0.0f;
    ((float*)lbin)[tid + 256] = 0.0f;
    if (tid == 0) sgmin = batch[base];
    __syncthreads();
    int gmin = sgmin;
    int nbase = base + chunk * 4;
    float r[8];
#pragma unroll
    for (int k = 0; k < 8; k++) r[k] = 0.0f;
    int cur = -1;
    for (int i = 0; i < 4; i++) {
        int n = nbase + i;
        if (n >= NN) break;
        int g = batch[n];
        if (g != cur) {
            if (cur >= 0) {
                int bin = cur - gmin;
                if (bin < 8) {
#pragma unroll
                    for (int k = 0; k < 8; k++) atomicAdd(&lbin[bin][fg * 8 + k], r[k]);
                } else {
#pragma unroll
                    for (int k = 0; k < 8; k++) atomicAdd(&gsum[cur * 64 + fg * 8 + k], r[k]);
                }
#pragma unroll
                for (int k = 0; k < 8; k++) r[k] = 0.0f;
            }
            cur = g;
        }
        add8(*(const float4*)(hb + (size_t)n * 64 + fg * 8), r);
    }
    if (cur >= 0) {
        int bin = cur - gmin;
        if (bin < 8) {
#pragma unroll
            for (int k = 0; k < 8; k++) atomicAdd(&lbin[bin][fg * 8 + k], r[k]);
        } else {
#pragma unroll
            for (int k = 0; k < 8; k++) atomicAdd(&gsum[cur * 64 + fg * 8 + k], r[k]);
        }
    }
    __syncthreads();
    int lastn = base + 127;
    if (lastn >= NN) lastn = NN - 1;
    int span = batch[lastn] - gmin + 1;
    if (span > 8) span = 8;
    for (int idx = tid; idx < span * 64; idx += 256) {
        int bin = idx >> 6;
        int f = idx & 63;
        float v = lbin[bin][f];
        if (v != 0.0f) atomicAdd(&gsum[(gmin + bin) * 64 + f], v);
    }
}

__global__ __launch_bounds__(128) void final_kernel(const float* __restrict__ gsum,
                                                    const float* __restrict__ gcnt,
                                                    const float* __restrict__ Wlin,
                                                    const float* __restrict__ blin,
                                                    float* __restrict__ out) {
    int t = threadIdx.x;  // 128 = G*C
    int g = t >> 1;
    int c = t & 1;
    float cnt = fmaxf(gcnt[g], 1.0f);
    float s = 0.0f;
#pragma unroll
    for (int k = 0; k < 64; k++) s = fmaf(gsum[g * 64 + k], Wlin[k * 2 + c], s);
    out[t] = s / cnt + blin[c];
}

extern "C" void kernel_launch(void* const* d_in, const int* in_sizes, int n_in,
                              void* d_out, int out_size, void* d_ws, size_t ws_size,
                              hipStream_t stream) {
    const float* x     = (const float*)d_in[0];
    const int*   ei    = (const int*)d_in[1];
    const int*   batch = (const int*)d_in[2];
    const float* W0    = (const float*)d_in[3];
    const float* b0    = (const float*)d_in[4];
    const float* W1    = (const float*)d_in[5];
    const float* b1    = (const float*)d_in[6];
    const float* W2    = (const float*)d_in[7];
    const float* b2    = (const float*)d_in[8];
    const float* Wlin  = (const float*)d_in[9];
    const float* blin  = (const float*)d_in[10];
    float* out = (float*)d_out;

    char* ws = (char*)d_ws;
    int*      rowStart = (int*)(ws + 0);
    int*      rowLen   = (int*)(ws + 400000);
    float*    dinv     = (float*)(ws + 800000);
    int*      srcs     = (int*)(ws + 1200000);
    __half*   u        = (__half*)(ws + 14012288);
    __half*   hb       = (__half*)(ws + 26812288);
    int*      tmp      = (int*)(ws + 26812288);   // overlaps hb; dead after bsort
    int*      perm     = (int*)(ws + 39612288);   // 400384 B, ends 40012672
    _Float16* Wh       = (_Float16*)(ws + 52424576);  // 3 x 32768 B, ends 52522880
    float*    gsum     = (float*)(ws + 52522880);
    float*    gcnt     = (float*)(ws + 52539264);
    int*      bcur     = (int*)(ws + 52539520);

    // zero gsum+gcnt+bcur (contiguous)
    hipMemsetAsync(ws + 52522880, 0, 18204, stream);

    // CSR build (+ degree-sorted perm), then merged prep (W swizzle + gcnt)
    bplace_kernel<<<cdiv_h(EE, 4096), 256, 0, stream>>>(ei, bcur, tmp);
    bsort_kernel<<<NBK, 256, 0, stream>>>(tmp, bcur, rowStart, rowLen, dinv, srcs, perm);
    prep_kernel<<<3 + cdiv_h(NN, 256), 256, 0, stream>>>(W0, W1, W2, Wh, batch, gcnt);

    int gemm_blocks = cdiv_h(NN / 16, 4);    // 6250 waves, 16 rows each
    int agg_blocks = NBK * 8;                // 3128 blocks x 32 slots

    gemm_mfma_f32_kernel<<<gemm_blocks, 256, 0, stream>>>(x, Wh, dinv, (_Float16*)u);
    agg_kernel<<<agg_blocks, 256, 0, stream>>>(u, srcs, rowStart, rowLen, dinv, perm, b0, hb);
    gemm_mfma_kernel<<<gemm_blocks, 256, 0, stream>>>((const _Float16*)hb, Wh + 16384, dinv, (_Float16*)u);
    agg_kernel<<<agg_blocks, 256, 0, stream>>>(u, srcs, rowStart, rowLen, dinv, perm, b1, hb);
    gemm_mfma_kernel<<<gemm_blocks, 256, 0, stream>>>((const _Float16*)hb, Wh + 32768, dinv, (_Float16*)u);
    agg_kernel<<<agg_blocks, 256, 0, stream>>>(u, srcs, rowStart, rowLen, dinv, perm, b2, hb);
    pool_kernel<<<cdiv_h(NN, 128), 256, 0, stream>>>(hb, batch, gsum);

    final_kernel<<<1, 128, 0, stream>>>(gsum, gcnt, Wlin, blin, out);
}